// Round 17
// baseline (214.608 us; speedup 1.0000x reference)
//
#include <hip/hip_runtime.h>
#include <stdint.h>

#define BATCH 256
#define NNODE 512
#define INP   57
#define HIDD  512
#define OUTD  57
#define SENTOFF (NNODE * HIDD)

typedef int i32x4 __attribute__((ext_vector_type(4)));

// Pre-pack B (i8) in MFMA fragment order, for the COLUMN-INTERLEAVED H layout:
// stored byte p of each 64-col block holds true col tloc(p)=16*(p&3)+(p>>2).
// kt 0..7: Wh rows (scale s1/127), k-side permuted to match stored child rows:
//   true_k = kt*64 + 16*(ksub&3) + (ksub>>2).
// kt 8: K-extension [Wx rows 0..56; b_ih; zeros] at HALF scale (s1/254), k-space
//   is the one-hot value space (not h) -> NOT permuted.
__global__ void pack_wq(const float* __restrict__ W_ih, const float* __restrict__ b_ih,
                        signed char* __restrict__ Wq){
  int idx = blockIdx.x * 256 + threadIdx.x;      // 0..294911
  int j    =  idx        & 15;
  int lane = (idx >> 4)  & 63;
  int nt   = (idx >> 10) & 31;
  int kt   =  idx >> 15;                         // 0..8
  int n    = nt * 16 + (lane & 15);
  int ksub = (lane >> 4) * 16 + j;               // 0..63 (stored-byte index)
  const float scale = 127.0f * sqrtf((float)(INP + HIDD));
  float wv; float sc = scale;
  if (kt < 8) {
    const int ktrue = kt * 64 + 16 * (ksub & 3) + (ksub >> 2);   // permuted k
    wv = W_ih[(size_t)(INP + ktrue) * HIDD + n];
  } else {
    sc = scale * 0.5f;                           // halved: global x2 in epilogue
    if (ksub < INP)       wv = W_ih[(size_t)ksub * HIDD + n];
    else if (ksub == INP) wv = b_ih[n];
    else                  wv = 0.0f;
  }
  float q = rintf(wv * sc);
  q = fminf(127.0f, fmaxf(-127.0f, q));
  Wq[idx] = (signed char)q;
}

// relaxed barrier: waits LDS ops only (slab/mirror writes); global H stores and
// prefetch loads stay in flight across it. Safe because fresh H stores are only
// read after a FULL __syncthreads at the next level-first barrier.
__device__ __forceinline__ void relaxed_barrier(){
  asm volatile("s_waitcnt lgkmcnt(0)" ::: "memory");
  __builtin_amdgcn_s_barrier();
  __builtin_amdgcn_sched_barrier(0);
}

// per-byte rounded signed average: (a+b+1)>>1 per i8 lane
__device__ __forceinline__ unsigned int avg_s8x4(unsigned int a, unsigned int b){
  unsigned int au = a ^ 0x80808080u, bu = b ^ 0x80808080u;
  unsigned int o = au | bu, x = au ^ bu;
  return ((o - ((x >> 1) & 0x7F7F7F7Fu)) ^ 0x80808080u);   // (a+b+1)>>1
}

struct Pref { uint4 l[2]; uint4 r[2]; };

// Load the SAFE (finalized) child rows of one chunk into registers; skip rows
// flagged hot (child is in the level currently being computed).
__device__ __forceinline__ void load_pref_safe(
    Pref& p, int m0, int Mcur, int w, int m16, int quad,
    const int* ord_s, const int* li_s, const int* ri_s, const int* hot_s,
    const signed char* Hb)
{
  const int koff = w * 64 + quad * 16;
  #pragma unroll
  for (int mt = 0; mt < 2; ++mt) {
    const int row  = mt * 16 + m16;
    const bool live = row < Mcur;
    const int pos  = m0 + row;
    const int node = live ? ord_s[pos] : -1;
    const int hb   = live ? hot_s[pos] : 0;
    const int loff = (node >= 0) ? li_s[node] : SENTOFF;
    const int roff = (node >= 0) ? ri_s[node] : SENTOFF;
    if (!(hb & 1)) p.l[mt] = *(const uint4*)(Hb + (size_t)(loff + koff));
    if (!(hb & 2)) p.r[mt] = *(const uint4*)(Hb + (size_t)(roff + koff));
  }
}

// Average the prefetched rows and write the A slabs (+ one-hot ext slabs).
__device__ __forceinline__ void write_pref(
    const Pref& p, int m0, int Mcur, int w, int lane, int m16, int quad,
    signed char* __restrict__ Ab, const int* ord_s, const int* val_s)
{
  #pragma unroll
  for (int mt = 0; mt < 2; ++mt) {
    uint4 o;
    o.x = avg_s8x4(p.l[mt].x, p.r[mt].x);
    o.y = avg_s8x4(p.l[mt].y, p.r[mt].y);
    o.z = avg_s8x4(p.l[mt].z, p.r[mt].z);
    o.w = avg_s8x4(p.l[mt].w, p.r[mt].w);
    *(uint4*)(Ab + (w * 2 + mt) * 1024 + lane * 16) = o;
  }
  if (w < 2) {                                   // ext slabs (one per m-tile)
    const int erow  = w * 16 + m16;
    const int enode = (erow < Mcur) ? ord_s[m0 + erow] : -1;
    const int v     = (enode >= 0) ? val_s[enode] : -1;
    signed char bytes[16];
    #pragma unroll
    for (int j = 0; j < 16; ++j) {
      const int ks = quad * 16 + j;
      bytes[j] = (enode >= 0 && (ks == v || ks == INP)) ? (signed char)127 : (signed char)0;
    }
    *(i32x4*)(Ab + (16 + w) * 1024 + lane * 16) = *(const i32x4*)bytes;
  }
}

// Level-first chunks: load the HOT children — from the LDS mirror when the
// previous level fit (<=32 nodes), else from global — then write all rows.
// hot_s encoding: bit0 l-hot, bit1 r-hot, bit2 l-mirror, bit3 r-mirror,
// bits 8-13 l mirror row, bits 16-21 r mirror row.
__device__ __forceinline__ void patch_and_write(
    Pref& p, int m0, int Mcur, int w, int lane, int m16, int quad,
    signed char* __restrict__ Ab,
    const int* ord_s, const int* li_s, const int* ri_s, const int* val_s,
    const int* hot_s, const signed char* Hb, const signed char* Hmir)
{
  const int koff = w * 64 + quad * 16;
  #pragma unroll
  for (int mt = 0; mt < 2; ++mt) {
    const int row  = mt * 16 + m16;
    const bool live = row < Mcur;
    const int pos  = m0 + row;
    const int hb   = live ? hot_s[pos] : 0;
    if (hb & 3) {
      const int node = ord_s[pos];
      if (hb & 1)
        p.l[mt] = (hb & 4)
          ? *(const uint4*)(Hmir + ((hb >> 8) & 63) * 512 + koff)
          : *(const uint4*)(Hb + (size_t)(li_s[node] + koff));
      if (hb & 2)
        p.r[mt] = (hb & 8)
          ? *(const uint4*)(Hmir + ((hb >> 16) & 63) * 512 + koff)
          : *(const uint4*)(Hb + (size_t)(ri_s[node] + koff));
    }
  }
  write_pref(p, m0, Mcur, w, lane, m16, quad, Ab, ord_s, val_s);
}

// shared epilogue: 127*tanh(2*acc*s1/127^2) = 127 - 254/(exp2(acc*SCLE)+1),
// SCLE = 4*log2(e)*s1/127^2 (x2 tanh-form, x2 averaged-A compensation).
#define SCLE_VAL (5.7707801635558536f / (16129.0f * 23.853720883753127f))  // sqrt(569)

__device__ __forceinline__ int tanh_q(int accv){
  const float x  = (float)accv * SCLE_VAL;
  const float e  = __builtin_amdgcn_exp2f(x);
  const float r  = __builtin_amdgcn_rcpf(e + 1.0f);
  return __float2int_rn(fmaf(-254.0f, r, 127.0f));
}

// MFMA + tanh epilogue for one chunk (slabs already resident in LDS).
// Packed-dword H store; when `mir` (level <=32 nodes) also write the LDS
// mirror so the next level's hot-patch reads LDS instead of global.
template<int NMT>
__device__ __forceinline__ void compute_chunk(
    int m0, int Mcur, int w, int lane, int m16, int quad,
    const signed char* __restrict__ Ab,
    const int* ordoff_s, const i32x4 (&Bv)[9][4], signed char* Hb,
    bool mir, signed char* __restrict__ Hmir)
{
  i32x4 acc[NMT][4];
  #pragma unroll
  for (int mt = 0; mt < NMT; ++mt)
    #pragma unroll
    for (int nt = 0; nt < 4; ++nt)
      acc[mt][nt] = (i32x4){0, 0, 0, 0};

  #pragma unroll
  for (int kt = 0; kt < 8; ++kt) {
    #pragma unroll
    for (int mt = 0; mt < NMT; ++mt) {
      i32x4 a = *(const i32x4*)(Ab + (kt * 2 + mt) * 1024 + lane * 16);
      #pragma unroll
      for (int nt = 0; nt < 4; ++nt)
        acc[mt][nt] = __builtin_amdgcn_mfma_i32_16x16x64_i8(a, Bv[kt][nt], acc[mt][nt], 0, 0, 0);
    }
  }
  #pragma unroll
  for (int mt = 0; mt < NMT; ++mt) {             // kt=8: one-hot Xp + bias (half-scale B)
    i32x4 ax = *(const i32x4*)(Ab + (16 + mt) * 1024 + lane * 16);
    #pragma unroll
    for (int nt = 0; nt < 4; ++nt)
      acc[mt][nt] = __builtin_amdgcn_mfma_i32_16x16x64_i8(ax, Bv[8][nt], acc[mt][nt], 0, 0, 0);
  }

  #pragma unroll
  for (int mt = 0; mt < NMT; ++mt) {
    #pragma unroll
    for (int rg = 0; rg < 4; ++rg) {
      const int rowc = mt * 16 + quad * 4 + rg;
      if (rowc < Mcur) {
        const int q0 = tanh_q(acc[mt][0][rg]) & 255;
        const int q1 = tanh_q(acc[mt][1][rg]) & 255;
        const int q2 = tanh_q(acc[mt][2][rg]) & 255;
        const int q3 = tanh_q(acc[mt][3][rg]);
        const int packed = q0 | (q1 << 8) | (q2 << 16) | (q3 << 24);
        const int col = w * 64 + m16 * 4;
        *(int*)(Hb + (size_t)ordoff_s[m0 + rowc] + col) = packed;
        if (mir) *(int*)(Hmir + rowc * 512 + col) = packed;
      }
    }
  }
}

// One block (512 threads = 8 waves = 2 waves/SIMD) per batch row.
// Flat pipelined chunk stream; FULL __syncthreads only at level-first barriers
// (prev level's global stores must be visible to this level's cold prefetches);
// all other barriers are lgkm-only raw s_barrier (H stores stay in flight).
__global__ __launch_bounds__(512, 2) void tree_rnn(
    const int* __restrict__ left, const int* __restrict__ right,
    const int* __restrict__ values,
    const float* __restrict__ W_ih, const float* __restrict__ b_ih,
    const float* __restrict__ W_o,  const float* __restrict__ b_o,
    const signed char* __restrict__ Wq,
    signed char* __restrict__ Hbuf, float* __restrict__ out)
{
  __shared__ __align__(16) signed char Abuf[2][18 * 1024]; // 8kt x 2mt + 2 ext slabs
  __shared__ __align__(16) signed char Hmir_s[32 * 512];   // prev-level mirror (16KB)
  __shared__ int li_s[NNODE], ri_s[NNODE], val_s[NNODE];
  __shared__ int lvl_s[NNODE], ord_s[NNODE], ordoff_s[NNODE];
  __shared__ int hot_s[NNODE], pos_s[NNODE];
  __shared__ int cnt_s[NNODE], cnt2_s[NNODE];
  __shared__ int offs_s[NNODE + 1];
  __shared__ int cdesc_s[NNODE];
  __shared__ int chg_s, lmax_s, nc_s;
  __shared__ float hroot_s[HIDD];
  __shared__ float red_s[OUTD][8];
  __shared__ float logit_s[64];

  const int b    = blockIdx.x;
  const int tid  = threadIdx.x;                  // 0..511, one per node in prepass
  const int lane = tid & 63;
  const int w    = tid >> 6;                     // 0..7
  signed char* Hb = Hbuf + (size_t)b * (NNODE + 1) * HIDD;

  // ---- load tree + init (ws is poisoned 0xAA: must zero sentinel row) ----
  li_s[tid]  = left  [b * NNODE + tid];
  ri_s[tid]  = right [b * NNODE + tid];
  val_s[tid] = values[b * NNODE + tid];
  lvl_s[tid] = 0; cnt_s[tid] = 0; cnt2_s[tid] = 0;
  if (tid < 128) ((unsigned int*)(Hb + (size_t)NNODE * HIDD))[tid] = 0;  // null-child row
  if (tid == 0) lmax_s = 0;
  __syncthreads();

  // ---- level fixpoint: lvl[i] = 1 + max(lvl[children]), null -> -1 ----
  for (;;) {
    if (tid == 0) chg_s = 0;
    __syncthreads();
    {
      int l = li_s[tid], r = ri_s[tid];
      int dl = (l >= 0) ? lvl_s[l] : -1;
      int dr = (r >= 0) ? lvl_s[r] : -1;
      int nl = 1 + (dl > dr ? dl : dr);
      if (nl > lvl_s[tid]) { lvl_s[tid] = nl; chg_s = 1; }   // monotone -> converges
    }
    __syncthreads();
    if (!chg_s) break;
  }

  // ---- bucket nodes by level (counting sort in LDS) ----
  const int myl = lvl_s[tid];
  {
    int ml = myl;
    #pragma unroll
    for (int m = 1; m < 64; m <<= 1) ml = max(ml, __shfl_xor(ml, m, 64));
    if (lane == 0) atomicMax(&lmax_s, ml);
    atomicAdd(&cnt_s[myl], 1);
  }
  __syncthreads();
  const int Lmax = lmax_s;
  if (tid == 0) {
    int acc = 0;
    for (int L = 0; L <= Lmax; ++L) { offs_s[L] = acc; acc += cnt_s[L]; }
    offs_s[Lmax + 1] = acc;                      // == 512
    int nc = 0;                                  // flat chunk list
    for (int L = 0; L <= Lmax; ++L)
      for (int m0 = offs_s[L]; m0 < offs_s[L + 1]; m0 += 32) {
        int sz = min(32, offs_s[L + 1] - m0);
        int fl = 0;
        if (m0 == offs_s[L]) {
          fl |= (1 << 30);                       // level-first
          if (offs_s[L + 1] - offs_s[L] <= 32) fl |= (1 << 29);   // mirror-write
        }
        cdesc_s[nc++] = m0 | (sz << 16) | fl;
      }
    nc_s = nc;
  }
  __syncthreads();
  {
    int pos = offs_s[myl] + atomicAdd(&cnt2_s[myl], 1);
    ord_s[pos] = tid;
    ordoff_s[pos] = tid * HIDD;                  // node byte-offset for epilogue
    pos_s[tid] = pos;                            // inverse map node -> position
  }
  __syncthreads();
  // hot flags per position: child hot iff parent in FIRST chunk of its level
  // AND child's level == L-1. Mirror-eligible iff prev level <= 32 nodes.
  {
    const int node = ord_s[tid];
    const int L = lvl_s[node];
    const int l = li_s[node], r = ri_s[node];    // still raw ids
    const bool first = (tid - offs_s[L]) < 32;
    const bool pmir = (L >= 1) && (offs_s[L] - offs_s[L - 1] <= 32);
    int h = 0;
    if (first && l >= 0 && lvl_s[l] == L - 1) {
      h |= 1;
      if (pmir) h |= 4 | ((pos_s[l] - offs_s[L - 1]) << 8);
    }
    if (first && r >= 0 && lvl_s[r] == L - 1) {
      h |= 2;
      if (pmir) h |= 8 | ((pos_s[r] - offs_s[L - 1]) << 16);
    }
    hot_s[tid] = h;
  }
  __syncthreads();
  // resolve child ids -> byte offsets
  {
    int l = li_s[tid], r = ri_s[tid];
    li_s[tid] = (l < 0 ? NNODE : l) * HIDD;
    ri_s[tid] = (r < 0 ? NNODE : r) * HIDD;
  }
  __syncthreads();

  const int m16  = lane & 15;
  const int quad = lane >> 4;

  // ---- this wave's B slice, loaded once: 9 kt x 4 n-tiles = 144 regs/lane ----
  i32x4 Bv[9][4];
  #pragma unroll
  for (int kt = 0; kt < 9; ++kt)
    #pragma unroll
    for (int nt = 0; nt < 4; ++nt)
      Bv[kt][nt] = *(const i32x4*)(Wq + ((size_t)(kt * 32 + 4 * w + nt) * 64 + lane) * 16);

  // ---- flat pipelined chunk stream ----
  const int NC = nc_s;
  Pref p;
  {
    const int d = cdesc_s[0];
    load_pref_safe(p, d & 0xFFFF, (d >> 16) & 0xFF, w, m16, quad,
                   ord_s, li_s, ri_s, hot_s, Hb);   // level 0: all safe (null children)
  }
  for (int gc = 0; gc < NC; ++gc) {
    const int d  = cdesc_s[gc];
    const int m0 = d & 0xFFFF, Mc = (d >> 16) & 0xFF;
    const bool first = (d >> 30) & 1;
    const bool mir   = (d >> 29) & 1;
    if (first) __syncthreads();                  // FULL: prev level's H stores visible
    else       relaxed_barrier();                // lgkm-only: stores stay in flight
    if (first) {
      patch_and_write(p, m0, Mc, w, lane, m16, quad, Abuf[gc & 1],
                      ord_s, li_s, ri_s, val_s, hot_s, Hb, Hmir_s);
      relaxed_barrier();                         // slab visible (LDS only)
    }
    const bool more = gc + 1 < NC;
    Pref pn; int m01 = 0, Mc1 = 0; bool f1 = false;
    if (more) {
      const int d1 = cdesc_s[gc + 1];
      m01 = d1 & 0xFFFF; Mc1 = (d1 >> 16) & 0xFF; f1 = (d1 >> 30) & 1;
      load_pref_safe(pn, m01, Mc1, w, m16, quad, ord_s, li_s, ri_s, hot_s, Hb);
    }
    const signed char* Ab = Abuf[gc & 1];
    if (Mc > 16)
      compute_chunk<2>(m0, Mc, w, lane, m16, quad, Ab, ordoff_s, Bv, Hb, mir, Hmir_s);
    else
      compute_chunk<1>(m0, Mc, w, lane, m16, quad, Ab, ordoff_s, Bv, Hb, mir, Hmir_s);
    if (more && !f1)                             // within-level: write slab now (R12)
      write_pref(pn, m01, Mc1, w, lane, m16, quad, Abuf[(gc + 1) & 1], ord_s, val_s);
    p = pn;
  }
  __syncthreads();                               // FULL: final level's H stores visible

  // ---- logits + log_softmax for this batch row ----
  {
    // un-permute the interleaved root row: stored byte tid -> true col tt
    const int t6 = tid & 63;
    const int tt = (tid & ~63) | (((t6 & 3) << 4) | (t6 >> 2));
    hroot_s[tt] = (float)Hb[(size_t)(NNODE - 1) * HIDD + tid] * (1.0f / 127.0f);
  }
  __syncthreads();
  {
    const int j = tid >> 3, part = tid & 7;      // 8 threads per output
    if (j < OUTD) {
      float p2 = 0.f;
      const int k0 = part * 64;
      for (int k = k0; k < k0 + 64; ++k)
        p2 += hroot_s[k] * W_o[(size_t)k * OUTD + j];
      red_s[j][part] = p2;
    }
  }
  __syncthreads();
  if (tid < OUTD) {
    float s = b_o[tid];
    #pragma unroll
    for (int pp = 0; pp < 8; ++pp) s += red_s[tid][pp];
    logit_s[tid] = s;
  }
  __syncthreads();
  if (w == 0) {
    float x = (lane < OUTD) ? logit_s[lane] : -1e30f;
    float mx = x;
    #pragma unroll
    for (int m = 1; m < 64; m <<= 1) mx = fmaxf(mx, __shfl_xor(mx, m, 64));
    float ex = (lane < OUTD) ? __expf(x - mx) : 0.f;
    float sm = ex;
    #pragma unroll
    for (int m = 1; m < 64; m <<= 1) sm += __shfl_xor(sm, m, 64);
    float ls = logf(sm);
    if (lane < OUTD) out[b * OUTD + lane] = x - mx - ls;
  }
}

extern "C" void kernel_launch(void* const* d_in, const int* in_sizes, int n_in,
                              void* d_out, int out_size, void* d_ws, size_t ws_size,
                              hipStream_t stream) {
  const int*   left   = (const int*)  d_in[0];
  const int*   right  = (const int*)  d_in[1];
  const int*   values = (const int*)  d_in[2];
  const float* W_ih   = (const float*)d_in[3];
  const float* b_ih   = (const float*)d_in[4];
  const float* W_o    = (const float*)d_in[5];
  const float* b_o    = (const float*)d_in[6];
  float* out = (float*)d_out;

  // workspace: [0, 512KB) packed B i8 (288KB used); then H: 256 x 513 x 512 i8 (~67 MB)
  signed char* Wq   = (signed char*)d_ws;
  signed char* Hbuf = (signed char*)((char*)d_ws + 512 * 1024);

  pack_wq<<<1152, 256, 0, stream>>>(W_ih, b_ih, Wq);
  tree_rnn<<<BATCH, 512, 0, stream>>>(left, right, values, W_ih, b_ih, W_o, b_o,
                                      Wq, Hbuf, out);
}

// Round 20
// 198.072 us; speedup vs baseline: 1.0835x; 1.0835x over previous
//
#include <hip/hip_runtime.h>
#include <stdint.h>
#include <math.h>

#define BATCH 256
#define NNODE 512
#define INP   57
#define HIDD  512
#define OUTD  57
#define SENTOFF (NNODE * HIDD)

typedef int i32x4 __attribute__((ext_vector_type(4)));

// Pre-pack B (i8) in MFMA fragment order, for the COLUMN-INTERLEAVED H layout:
// stored byte p of each 64-col block holds true col tloc(p)=16*(p&3)+(p>>2).
// kt 0..7: Wh rows (scale s1/127), k-side permuted to match stored child rows:
//   true_k = kt*64 + 16*(ksub&3) + (ksub>>2).
// kt 8: K-extension [Wx rows 0..56; b_ih; zeros] at HALF scale (s1/254), k-space
//   is the one-hot value space (not h) -> NOT permuted.
__global__ void pack_wq(const float* __restrict__ W_ih, const float* __restrict__ b_ih,
                        signed char* __restrict__ Wq){
  int idx = blockIdx.x * 256 + threadIdx.x;      // 0..294911
  int j    =  idx        & 15;
  int lane = (idx >> 4)  & 63;
  int nt   = (idx >> 10) & 31;
  int kt   =  idx >> 15;                         // 0..8
  int n    = nt * 16 + (lane & 15);
  int ksub = (lane >> 4) * 16 + j;               // 0..63 (stored-byte index)
  const float scale = 127.0f * sqrtf((float)(INP + HIDD));
  float wv; float sc = scale;
  if (kt < 8) {
    const int ktrue = kt * 64 + 16 * (ksub & 3) + (ksub >> 2);   // permuted k
    wv = W_ih[(size_t)(INP + ktrue) * HIDD + n];
  } else {
    sc = scale * 0.5f;                           // halved: global x2 in epilogue
    if (ksub < INP)       wv = W_ih[(size_t)ksub * HIDD + n];
    else if (ksub == INP) wv = b_ih[n];
    else                  wv = 0.0f;
  }
  float q = rintf(wv * sc);
  q = fminf(127.0f, fmaxf(-127.0f, q));
  Wq[idx] = (signed char)q;
}

// per-byte rounded signed average: (a+b+1)>>1 per i8 lane
__device__ __forceinline__ unsigned int avg_s8x4(unsigned int a, unsigned int b){
  unsigned int au = a ^ 0x80808080u, bu = b ^ 0x80808080u;
  unsigned int o = au | bu, x = au ^ bu;
  return ((o - ((x >> 1) & 0x7F7F7F7Fu)) ^ 0x80808080u);   // (a+b+1)>>1
}

struct Pref { uint4 l[2]; uint4 r[2]; };

// Load the SAFE (finalized) child rows of one chunk into registers; skip rows
// flagged hot (child is in the level currently being computed).
__device__ __forceinline__ void load_pref_safe(
    Pref& p, int m0, int Mcur, int w, int m16, int quad,
    const int* ord_s, const int* li_s, const int* ri_s, const int* hot_s,
    const signed char* Hb)
{
  const int koff = w * 64 + quad * 16;
  #pragma unroll
  for (int mt = 0; mt < 2; ++mt) {
    const int row  = mt * 16 + m16;
    const bool live = row < Mcur;
    const int pos  = m0 + row;
    const int node = live ? ord_s[pos] : -1;
    const int hb   = live ? hot_s[pos] : 0;
    const int loff = (node >= 0) ? li_s[node] : SENTOFF;
    const int roff = (node >= 0) ? ri_s[node] : SENTOFF;
    if (!(hb & 1)) p.l[mt] = *(const uint4*)(Hb + (size_t)(loff + koff));
    if (!(hb & 2)) p.r[mt] = *(const uint4*)(Hb + (size_t)(roff + koff));
  }
}

// Average the prefetched rows and write the A slabs (+ one-hot ext slabs).
__device__ __forceinline__ void write_pref(
    const Pref& p, int m0, int Mcur, int w, int lane, int m16, int quad,
    signed char* __restrict__ Ab, const int* ord_s, const int* val_s)
{
  #pragma unroll
  for (int mt = 0; mt < 2; ++mt) {
    uint4 o;
    o.x = avg_s8x4(p.l[mt].x, p.r[mt].x);
    o.y = avg_s8x4(p.l[mt].y, p.r[mt].y);
    o.z = avg_s8x4(p.l[mt].z, p.r[mt].z);
    o.w = avg_s8x4(p.l[mt].w, p.r[mt].w);
    *(uint4*)(Ab + (w * 2 + mt) * 1024 + lane * 16) = o;
  }
  if (w < 2) {                                   // ext slabs (one per m-tile)
    const int erow  = w * 16 + m16;
    const int enode = (erow < Mcur) ? ord_s[m0 + erow] : -1;
    const int v     = (enode >= 0) ? val_s[enode] : -1;
    signed char bytes[16];
    #pragma unroll
    for (int j = 0; j < 16; ++j) {
      const int ks = quad * 16 + j;
      bytes[j] = (enode >= 0 && (ks == v || ks == INP)) ? (signed char)127 : (signed char)0;
    }
    *(i32x4*)(Ab + (16 + w) * 1024 + lane * 16) = *(const i32x4*)bytes;
  }
}

// Level-first chunks: load the HOT children (just finalized at the barrier),
// then write all rows + ext slabs.
__device__ __forceinline__ void patch_and_write(
    Pref& p, int m0, int Mcur, int w, int lane, int m16, int quad,
    signed char* __restrict__ Ab,
    const int* ord_s, const int* li_s, const int* ri_s, const int* val_s,
    const int* hot_s, const signed char* Hb)
{
  const int koff = w * 64 + quad * 16;
  #pragma unroll
  for (int mt = 0; mt < 2; ++mt) {
    const int row  = mt * 16 + m16;
    const bool live = row < Mcur;
    const int pos  = m0 + row;
    const int hb   = live ? hot_s[pos] : 0;
    if (hb) {
      const int node = ord_s[pos];
      if (hb & 1) p.l[mt] = *(const uint4*)(Hb + (size_t)(li_s[node] + koff));
      if (hb & 2) p.r[mt] = *(const uint4*)(Hb + (size_t)(ri_s[node] + koff));
    }
  }
  write_pref(p, m0, Mcur, w, lane, m16, quad, Ab, ord_s, val_s);
}

// tanh argument scale: v = acc * VSCALE, VSCALE = 2*s1/127^2 (x2 tanh-form
// folding of the averaged-A compensation). NOTE: R18/R19 bug was using the
// exp2-exponent scale (x 2*log2e too big) as the tanhf argument.
#define VSCALE_VAL (2.0f / (16129.0f * 23.853720883753127f))   // sqrt(569)=23.85372...

// LUT tanh: idx = clamp((acc + 655360 + 512) >> 10, 0, 1279).
// Bin center acc_c(i) = i*1024 - 655360 -> lut[i] = rn(127*tanh(acc_c*VSCALE)).
// Half-bin err = 127*512*VSCALE = 0.34 LSB; edges: |v|=3.41 -> rn(127*tanh)=127.
__device__ __forceinline__ int tanh_q_lut(int accv, const signed char* lut){
  int idx = (accv + 655872) >> 10;
  idx = min(max(idx, 0), 1279);
  return lut[idx];
}

// MFMA + LUT-tanh epilogue for one chunk (slabs already resident in LDS).
// Packed-dword H store: lane (w,m16,quad) packs its 4 nt-outputs (true cols
// 16*nt+m16 of block w) into stored bytes w*64 + m16*4 + nt.
template<int NMT>
__device__ __forceinline__ void compute_chunk(
    int m0, int Mcur, int w, int lane, int m16, int quad,
    const signed char* __restrict__ Ab,
    const int* ordoff_s, const i32x4 (&Bv)[9][4], signed char* Hb,
    const signed char* __restrict__ lut)
{
  i32x4 acc[NMT][4];
  #pragma unroll
  for (int mt = 0; mt < NMT; ++mt)
    #pragma unroll
    for (int nt = 0; nt < 4; ++nt)
      acc[mt][nt] = (i32x4){0, 0, 0, 0};

  #pragma unroll
  for (int kt = 0; kt < 8; ++kt) {
    #pragma unroll
    for (int mt = 0; mt < NMT; ++mt) {
      i32x4 a = *(const i32x4*)(Ab + (kt * 2 + mt) * 1024 + lane * 16);
      #pragma unroll
      for (int nt = 0; nt < 4; ++nt)
        acc[mt][nt] = __builtin_amdgcn_mfma_i32_16x16x64_i8(a, Bv[kt][nt], acc[mt][nt], 0, 0, 0);
    }
  }
  #pragma unroll
  for (int mt = 0; mt < NMT; ++mt) {             // kt=8: one-hot Xp + bias (half-scale B)
    i32x4 ax = *(const i32x4*)(Ab + (16 + mt) * 1024 + lane * 16);
    #pragma unroll
    for (int nt = 0; nt < 4; ++nt)
      acc[mt][nt] = __builtin_amdgcn_mfma_i32_16x16x64_i8(ax, Bv[8][nt], acc[mt][nt], 0, 0, 0);
  }

  #pragma unroll
  for (int mt = 0; mt < NMT; ++mt) {
    #pragma unroll
    for (int rg = 0; rg < 4; ++rg) {
      const int rowc = mt * 16 + quad * 4 + rg;
      if (rowc < Mcur) {
        const int q0 = tanh_q_lut(acc[mt][0][rg], lut) & 255;
        const int q1 = tanh_q_lut(acc[mt][1][rg], lut) & 255;
        const int q2 = tanh_q_lut(acc[mt][2][rg], lut) & 255;
        const int q3 = tanh_q_lut(acc[mt][3][rg], lut);
        const int packed = q0 | (q1 << 8) | (q2 << 16) | (q3 << 24);
        *(int*)(Hb + (size_t)ordoff_s[m0 + rowc] + (w * 64 + m16 * 4)) = packed;
      }
    }
  }
}

// One block (512 threads = 8 waves = 2 waves/SIMD) per batch row.
// Level-scheduled tree RNN as a flat pipelined chunk stream: safe (finalized)
// child rows prefetched into regs during the previous chunk's compute;
// level-first chunks patch their hot children (just stored, L2-hot) after the
// level barrier. Within-level chunks: single barrier (R12 pipeline).
__global__ __launch_bounds__(512, 2) void tree_rnn(
    const int* __restrict__ left, const int* __restrict__ right,
    const int* __restrict__ values,
    const float* __restrict__ W_ih, const float* __restrict__ b_ih,
    const float* __restrict__ W_o,  const float* __restrict__ b_o,
    const signed char* __restrict__ Wq,
    signed char* __restrict__ Hbuf, float* __restrict__ out)
{
  __shared__ __align__(16) signed char Abuf[2][18 * 1024]; // 8kt x 2mt + 2 ext slabs
  __shared__ signed char tanhlut_s[1280];
  __shared__ int li_s[NNODE], ri_s[NNODE], val_s[NNODE];
  __shared__ int lvl_s[NNODE], ord_s[NNODE], ordoff_s[NNODE], hot_s[NNODE];
  __shared__ int cnt_s[NNODE], cnt2_s[NNODE];
  __shared__ int offs_s[NNODE + 1];
  __shared__ int cdesc_s[NNODE];
  __shared__ int chg_s, lmax_s, nc_s;
  __shared__ float hroot_s[HIDD];
  __shared__ float red_s[OUTD][8];
  __shared__ float logit_s[64];

  const int b    = blockIdx.x;
  const int tid  = threadIdx.x;                  // 0..511, one per node in prepass
  const int lane = tid & 63;
  const int w    = tid >> 6;                     // 0..7
  signed char* Hb = Hbuf + (size_t)b * (NNODE + 1) * HIDD;

  // ---- load tree + init (ws is poisoned 0xAA: must zero sentinel row) ----
  li_s[tid]  = left  [b * NNODE + tid];
  ri_s[tid]  = right [b * NNODE + tid];
  val_s[tid] = values[b * NNODE + tid];
  lvl_s[tid] = 0; cnt_s[tid] = 0; cnt2_s[tid] = 0;
  if (tid < 128) ((unsigned int*)(Hb + (size_t)NNODE * HIDD))[tid] = 0;  // null-child row
  if (tid == 0) lmax_s = 0;
  // build LUT once per block (strided: 1280 entries > 512 threads)
  for (int i = tid; i < 1280; i += 512) {
    const float xc = (float)((i << 10) - 655360) * VSCALE_VAL;
    tanhlut_s[i] = (signed char)__float2int_rn(127.0f * tanhf(xc));
  }
  __syncthreads();

  // ---- level fixpoint: lvl[i] = 1 + max(lvl[children]), null -> -1 ----
  for (;;) {
    if (tid == 0) chg_s = 0;
    __syncthreads();
    {
      int l = li_s[tid], r = ri_s[tid];
      int dl = (l >= 0) ? lvl_s[l] : -1;
      int dr = (r >= 0) ? lvl_s[r] : -1;
      int nl = 1 + (dl > dr ? dl : dr);
      if (nl > lvl_s[tid]) { lvl_s[tid] = nl; chg_s = 1; }   // monotone -> converges
    }
    __syncthreads();
    if (!chg_s) break;
  }

  // ---- bucket nodes by level (counting sort in LDS) ----
  const int myl = lvl_s[tid];
  {
    int ml = myl;
    #pragma unroll
    for (int m = 1; m < 64; m <<= 1) ml = max(ml, __shfl_xor(ml, m, 64));
    if (lane == 0) atomicMax(&lmax_s, ml);
    atomicAdd(&cnt_s[myl], 1);
  }
  __syncthreads();
  const int Lmax = lmax_s;
  if (tid == 0) {
    int acc = 0;
    for (int L = 0; L <= Lmax; ++L) { offs_s[L] = acc; acc += cnt_s[L]; }
    offs_s[Lmax + 1] = acc;                      // == 512
    int nc = 0;                                  // flat chunk list
    for (int L = 0; L <= Lmax; ++L)
      for (int m0 = offs_s[L]; m0 < offs_s[L + 1]; m0 += 32) {
        int sz = min(32, offs_s[L + 1] - m0);
        cdesc_s[nc++] = m0 | (sz << 16) | ((m0 == offs_s[L]) ? (1 << 30) : 0);
      }
    nc_s = nc;
  }
  __syncthreads();
  {
    int pos = offs_s[myl] + atomicAdd(&cnt2_s[myl], 1);
    ord_s[pos] = tid;
    ordoff_s[pos] = tid * HIDD;                  // node byte-offset for epilogue
  }
  __syncthreads();
  // hot flags per position: child is hot iff parent is in the FIRST chunk of
  // its level AND child's level == parent's level - 1 (being computed while
  // this chunk's prefetch is in flight).
  {
    const int node = ord_s[tid];
    const int L = lvl_s[node];
    const int l = li_s[node], r = ri_s[node];    // still raw ids
    const bool first = (tid - offs_s[L]) < 32;
    int h = 0;
    if (first && l >= 0 && lvl_s[l] == L - 1) h |= 1;
    if (first && r >= 0 && lvl_s[r] == L - 1) h |= 2;
    hot_s[tid] = h;
  }
  __syncthreads();
  // resolve child ids -> byte offsets
  {
    int l = li_s[tid], r = ri_s[tid];
    li_s[tid] = (l < 0 ? NNODE : l) * HIDD;
    ri_s[tid] = (r < 0 ? NNODE : r) * HIDD;
  }
  __syncthreads();

  const int m16  = lane & 15;
  const int quad = lane >> 4;

  // ---- this wave's B slice, loaded once: 9 kt x 4 n-tiles = 144 regs/lane ----
  i32x4 Bv[9][4];
  #pragma unroll
  for (int kt = 0; kt < 9; ++kt)
    #pragma unroll
    for (int nt = 0; nt < 4; ++nt)
      Bv[kt][nt] = *(const i32x4*)(Wq + ((size_t)(kt * 32 + 4 * w + nt) * 64 + lane) * 16);

  // ---- flat pipelined chunk stream ----
  const int NC = nc_s;
  Pref p;
  {
    const int d = cdesc_s[0];
    load_pref_safe(p, d & 0xFFFF, (d >> 16) & 0x3FFF, w, m16, quad,
                   ord_s, li_s, ri_s, hot_s, Hb);   // level 0: all safe (null children)
  }
  for (int gc = 0; gc < NC; ++gc) {
    const int d  = cdesc_s[gc];
    const int m0 = d & 0xFFFF, Mc = (d >> 16) & 0x3FFF;
    const bool first = (d >> 30) & 1;
    __syncthreads();                             // A: prev compute + slab/H stores visible
    if (first) {
      patch_and_write(p, m0, Mc, w, lane, m16, quad, Abuf[gc & 1],
                      ord_s, li_s, ri_s, val_s, hot_s, Hb);
      __syncthreads();                           // B: slab visible (cheap)
    }
    const bool more = gc + 1 < NC;
    Pref pn; int m01 = 0, Mc1 = 0; bool f1 = false;
    if (more) {
      const int d1 = cdesc_s[gc + 1];
      m01 = d1 & 0xFFFF; Mc1 = (d1 >> 16) & 0x3FFF; f1 = (d1 >> 30) & 1;
      load_pref_safe(pn, m01, Mc1, w, m16, quad, ord_s, li_s, ri_s, hot_s, Hb);
    }
    const signed char* Ab = Abuf[gc & 1];
    if (Mc > 16)
      compute_chunk<2>(m0, Mc, w, lane, m16, quad, Ab, ordoff_s, Bv, Hb, tanhlut_s);
    else
      compute_chunk<1>(m0, Mc, w, lane, m16, quad, Ab, ordoff_s, Bv, Hb, tanhlut_s);
    if (more && !f1)                             // within-level: write slab now (R12)
      write_pref(pn, m01, Mc1, w, lane, m16, quad, Abuf[(gc + 1) & 1], ord_s, val_s);
    p = pn;
  }
  __syncthreads();                               // final level's H stores visible

  // ---- logits + log_softmax for this batch row ----
  {
    // un-permute the interleaved root row: stored byte tid -> true col tt
    const int t6 = tid & 63;
    const int tt = (tid & ~63) | (((t6 & 3) << 4) | (t6 >> 2));
    hroot_s[tt] = (float)Hb[(size_t)(NNODE - 1) * HIDD + tid] * (1.0f / 127.0f);
  }
  __syncthreads();
  {
    const int j = tid >> 3, part = tid & 7;      // 8 threads per output
    if (j < OUTD) {
      float p2 = 0.f;
      const int k0 = part * 64;
      for (int k = k0; k < k0 + 64; ++k)
        p2 += hroot_s[k] * W_o[(size_t)k * OUTD + j];
      red_s[j][part] = p2;
    }
  }
  __syncthreads();
  if (tid < OUTD) {
    float s = b_o[tid];
    #pragma unroll
    for (int pp = 0; pp < 8; ++pp) s += red_s[tid][pp];
    logit_s[tid] = s;
  }
  __syncthreads();
  if (w == 0) {
    float x = (lane < OUTD) ? logit_s[lane] : -1e30f;
    float mx = x;
    #pragma unroll
    for (int m = 1; m < 64; m <<= 1) mx = fmaxf(mx, __shfl_xor(mx, m, 64));
    float ex = (lane < OUTD) ? __expf(x - mx) : 0.f;
    float sm = ex;
    #pragma unroll
    for (int m = 1; m < 64; m <<= 1) sm += __shfl_xor(sm, m, 64);
    float ls = logf(sm);
    if (lane < OUTD) out[b * OUTD + lane] = x - mx - ls;
  }
}

extern "C" void kernel_launch(void* const* d_in, const int* in_sizes, int n_in,
                              void* d_out, int out_size, void* d_ws, size_t ws_size,
                              hipStream_t stream) {
  const int*   left   = (const int*)  d_in[0];
  const int*   right  = (const int*)  d_in[1];
  const int*   values = (const int*)  d_in[2];
  const float* W_ih   = (const float*)d_in[3];
  const float* b_ih   = (const float*)d_in[4];
  const float* W_o    = (const float*)d_in[5];
  const float* b_o    = (const float*)d_in[6];
  float* out = (float*)d_out;

  // workspace: [0, 512KB) packed B i8 (288KB used); then H: 256 x 513 x 512 i8 (~67 MB)
  signed char* Wq   = (signed char*)d_ws;
  signed char* Hbuf = (signed char*)((char*)d_ws + 512 * 1024);

  pack_wq<<<1152, 256, 0, stream>>>(W_ih, b_ih, Wq);
  tree_rnn<<<BATCH, 512, 0, stream>>>(left, right, values, W_ih, b_ih, W_o, b_o,
                                      Wq, Hbuf, out);
}